// Round 12
// baseline (151.306 us; speedup 1.0000x reference)
//
#include <hip/hip_runtime.h>
#include <hip/hip_bf16.h>
#include <math.h>

// Problem constants: H=8, d_model=256, N=128, d_k=32, B=32, rows=4096

typedef short short8 __attribute__((ext_vector_type(8)));
typedef float f32x4 __attribute__((ext_vector_type(4)));

union V8 { uint4 u; short8 s; };

__device__ __forceinline__ float gelu_f(float x) {
    float inner = 0.7978845608028654f * (x + 0.044715f * x * x * x);
    return 0.5f * x * (1.0f + tanhf(inner));
}
__device__ __forceinline__ void split_bf16(float x, ushort& h, ushort& l) {
    __hip_bfloat16 bh = __float2bfloat16(x);          // RN
    float hf = __bfloat162float(bh);
    __hip_bfloat16 bl = __float2bfloat16(x - hf);
    h = __builtin_bit_cast(ushort, bh);
    l = __builtin_bit_cast(ushort, bl);
}
__device__ __forceinline__ ushort bf16bits(float x) {
    return __builtin_bit_cast(ushort, __float2bfloat16(x));
}
__device__ __forceinline__ float bits_to_f(ushort v) {
    return __builtin_bit_cast(float, ((uint)v) << 16);
}
__device__ __forceinline__ short8 lds_frag(const ushort* p) {
    V8 v; v.u = *(const uint4*)p; return v.s;
}

// Frag layout for prepped weights: elem (k,n) of mat m lives at
//   m*65536 + ((tg*8+ks)*64 + lane)*8 + j
// with tg=n>>4, lr=n&15, ks=k>>5, quad=(k>>3)&3, j=k&7, lane=quad*16+lr.
// Mats: 0=mlp_w1 1=mlp_w2 2=wq 3=wk 4=wv 5=out_w (6/7 unused since featproj
// converts fc_out_w inline).

// ---------------------------------------------------------------------------
// Dispatch 1: blocks 0..47 = wprep paired jobs (mats 0..5, 96 jobs);
//             blocks 48..111 = featproj with INLINE fc_out_w conversion
//             (same split_bf16 → bit-identical A/Bm; no wprep dependency).
// 512 threads.
// ---------------------------------------------------------------------------
__global__ __launch_bounds__(512) void k_d1(
    const float* __restrict__ mlp_w1, const float* __restrict__ mlp_w2,
    const float* __restrict__ wq, const float* __restrict__ wk,
    const float* __restrict__ wv, const float* __restrict__ out_w,
    const float* __restrict__ fc_out_w, const float* __restrict__ memory_w,
    ushort* __restrict__ hi, ushort* __restrict__ lo,
    float* __restrict__ A, float* __restrict__ Bm) {
    __shared__ __align__(16) union {
        float xs[2][32 * 132];                               // wprep 33.8 KB
        struct { ushort xhi[16 * 264], xlo[16 * 264]; } f;   // featproj 16.9 KB
    } sm;
    int bx = blockIdx.x, t = threadIdx.x;
    if (bx < 48) {
        // ---- two wprep jobs per block; job in 0..95, m in 0..5
        int half = t >> 8, tl = t & 255;
        int job = bx * 2 + half;
        int m = job >> 4, ks = (job >> 1) & 7, nh = job & 1;
        const float* W = m == 0 ? mlp_w1 : m == 1 ? mlp_w2 : m == 2 ? wq :
                         m == 3 ? wk : m == 4 ? wv : out_w;
        ushort* Hm = hi + m * 65536;
        ushort* Lm = lo + m * 65536;
        float* xs = sm.xs[half];
        #pragma unroll
        for (int p = 0; p < 4; ++p) {
            int idx = p * 256 + tl;
            int row = idx >> 5, c4 = (idx & 31) * 4;
            *(float4*)(xs + row * 132 + c4) =
                *(const float4*)(W + (ks * 32 + row) * 256 + nh * 128 + c4);
        }
        __syncthreads();
        int lane = tl & 63, lr = lane & 15, quad = lane >> 4;
        #pragma unroll
        for (int it = 0; it < 2; ++it) {
            int tgl = (tl >> 6) + 4 * it;
            int tg = nh * 8 + tgl;
            int nl = tgl * 16 + lr;
            ushort hb[8], lb[8];
            #pragma unroll
            for (int j = 0; j < 8; ++j)
                split_bf16(xs[(quad * 8 + j) * 132 + nl], hb[j], lb[j]);
            uint4 ph = { (uint)hb[0] | ((uint)hb[1] << 16), (uint)hb[2] | ((uint)hb[3] << 16),
                         (uint)hb[4] | ((uint)hb[5] << 16), (uint)hb[6] | ((uint)hb[7] << 16) };
            uint4 pl = { (uint)lb[0] | ((uint)lb[1] << 16), (uint)lb[2] | ((uint)lb[3] << 16),
                         (uint)lb[4] | ((uint)lb[5] << 16), (uint)lb[6] | ((uint)lb[7] << 16) };
            int idx = ((tg * 8 + ks) * 64 + lane) * 8;
            *(uint4*)(Hm + idx) = ph;
            *(uint4*)(Lm + idx) = pl;
        }
    } else {
        // ---- featproj: rt = bx-48; one staged tile serves all 8 (msel,cq);
        //      B-frags converted inline from fp32 fc_out_w (L2-resident).
        int rt = bx - 48;
        #pragma unroll
        for (int ii = 0; ii < 2; ++ii) {
            int f4 = ii * 512 + t;
            int rr = f4 >> 6, c = (f4 & 63) * 4;
            int r = rt * 16 + rr;
            int h = r >> 7, n = r & 127;
            float4 xv = *(const float4*)(memory_w + n * 2048 + h * 256 + c);
            ushort hh[4], ll[4];
            split_bf16(xv.x, hh[0], ll[0]); split_bf16(xv.y, hh[1], ll[1]);
            split_bf16(xv.z, hh[2], ll[2]); split_bf16(xv.w, hh[3], ll[3]);
            uint2 ph = { (uint)hh[0] | ((uint)hh[1] << 16), (uint)hh[2] | ((uint)hh[3] << 16) };
            uint2 pl = { (uint)ll[0] | ((uint)ll[1] << 16), (uint)ll[2] | ((uint)ll[3] << 16) };
            *(uint2*)(sm.f.xhi + rr * 264 + c) = ph;
            *(uint2*)(sm.f.xlo + rr * 264 + c) = pl;
        }
        __syncthreads();
        int lane = t & 63, w = t >> 6;
        int lr = lane & 15, quad = lane >> 4;
        int msel = w & 1, cq = w >> 1;
        const float* Wf = fc_out_w + msel * 65536;
        const ushort* ah = sm.f.xhi + lr * 264 + quad * 8;
        const ushort* al = sm.f.xlo + lr * 264 + quad * 8;
        float* O = msel ? Bm : A;
        #pragma unroll
        for (int i = 0; i < 4; ++i) {
            int tg = cq * 4 + i;
            int n = tg * 16 + lr;
            f32x4 acc = {};
            #pragma unroll
            for (int ks = 0; ks < 8; ++ks) {
                short8 a_h = lds_frag(ah + ks * 32);
                short8 a_l = lds_frag(al + ks * 32);
                int k0 = ks * 32 + quad * 8;
                V8 bh, bl;
                #pragma unroll
                for (int j = 0; j < 8; ++j) {
                    ushort hh, ll;
                    split_bf16(Wf[(k0 + j) * 256 + n], hh, ll);
                    bh.s[j] = (short)hh;
                    bl.s[j] = (short)ll;
                }
                acc = __builtin_amdgcn_mfma_f32_16x16x32_bf16(a_h, bh.s, acc, 0, 0, 0);
                acc = __builtin_amdgcn_mfma_f32_16x16x32_bf16(a_l, bh.s, acc, 0, 0, 0);
                acc = __builtin_amdgcn_mfma_f32_16x16x32_bf16(a_h, bl.s, acc, 0, 0, 0);
            }
            #pragma unroll
            for (int r = 0; r < 4; ++r)
                O[(rt * 16 + quad * 4 + r) * 256 + n] = acc[r];
        }
    }
}

// ---------------------------------------------------------------------------
// Dispatch 2: blocks 0..255 = fused3 (mlp1->mlp2->qkv, bf16 out);
//             blocks 256..511 = conn (32i x 16j tiles).
// fused3 reads wf mats 0..4 (D1); conn reads A/Bm (D1). Writes disjoint.
// ---------------------------------------------------------------------------
__global__ __launch_bounds__(512) void k_d2(
    const float* __restrict__ X,
    const ushort* __restrict__ Whi, const ushort* __restrict__ Wlo,
    const float* __restrict__ b1, const float* __restrict__ b2,
    const float* __restrict__ Bq, const float* __restrict__ Bk,
    const float* __restrict__ Bv,
    ushort* __restrict__ Q, ushort* __restrict__ K, ushort* __restrict__ V,
    const float* __restrict__ A, const float* __restrict__ Bmat,
    const float* __restrict__ fc_out_b, const float* __restrict__ fc_cat_w,
    const float* __restrict__ fc_cat_b, const float* __restrict__ gumbel_u,
    ushort* __restrict__ maskb) {
    __shared__ __align__(16) union {
        struct {
            ushort aHi[16 * 264], aLo[16 * 264];
            ushort bHi[16 * 264], bLo[16 * 264];
        } g;                                                   // 33.8 KB
        struct { float sA[16 * 260]; float sB[32 * 260]; } c;  // 49.9 KB
    } sm;
    int bx = blockIdx.x, t = threadIdx.x;
    if (bx < 256) {
        // ================= fused3 (identical math to R11) =================
        int r0 = bx * 16;
        #pragma unroll
        for (int ii = 0; ii < 2; ++ii) {
            int f4 = ii * 512 + t;
            int row = f4 >> 6, c = (f4 & 63) * 4;
            float4 xv = *(const float4*)(X + (r0 + row) * 256 + c);
            ushort h[4], l[4];
            split_bf16(xv.x, h[0], l[0]); split_bf16(xv.y, h[1], l[1]);
            split_bf16(xv.z, h[2], l[2]); split_bf16(xv.w, h[3], l[3]);
            uint2 ph = { (uint)h[0] | ((uint)h[1] << 16), (uint)h[2] | ((uint)h[3] << 16) };
            uint2 pl = { (uint)l[0] | ((uint)l[1] << 16), (uint)l[2] | ((uint)l[3] << 16) };
            *(uint2*)(sm.g.aHi + row * 264 + c) = ph;
            *(uint2*)(sm.g.aLo + row * 264 + c) = pl;
        }
        __syncthreads();
        int lane = t & 63, w = t >> 6;
        int lr = lane & 15, quad = lane >> 4;
        int aoff = lr * 264 + quad * 8;
        // stage 1: mlp1 + gelu
        {
            const uint4* H4 = (const uint4*)(Whi + 0 * 65536);
            const uint4* L4 = (const uint4*)(Wlo + 0 * 65536);
            f32x4 acc[2] = {};
            #pragma unroll
            for (int ks = 0; ks < 8; ++ks) {
                short8 a_h = lds_frag(sm.g.aHi + aoff + ks * 32);
                short8 a_l = lds_frag(sm.g.aLo + aoff + ks * 32);
                #pragma unroll
                for (int ti = 0; ti < 2; ++ti) {
                    int off = ((w * 2 + ti) * 8 + ks) * 64 + lane;
                    V8 bh, bl; bh.u = H4[off]; bl.u = L4[off];
                    acc[ti] = __builtin_amdgcn_mfma_f32_16x16x32_bf16(a_h, bh.s, acc[ti], 0, 0, 0);
                    acc[ti] = __builtin_amdgcn_mfma_f32_16x16x32_bf16(a_l, bh.s, acc[ti], 0, 0, 0);
                    acc[ti] = __builtin_amdgcn_mfma_f32_16x16x32_bf16(a_h, bl.s, acc[ti], 0, 0, 0);
                }
            }
            #pragma unroll
            for (int ti = 0; ti < 2; ++ti) {
                int n0 = (w * 2 + ti) * 16 + lr;
                float bb = b1[n0];
                #pragma unroll
                for (int r = 0; r < 4; ++r) {
                    float o = gelu_f(acc[ti][r] + bb);
                    ushort hh, ll; split_bf16(o, hh, ll);
                    int ad = (quad * 4 + r) * 264 + n0;
                    sm.g.bHi[ad] = hh; sm.g.bLo[ad] = ll;
                }
            }
        }
        __syncthreads();
        // stage 2: mlp2
        {
            const uint4* H4 = (const uint4*)(Whi + 1 * 65536);
            const uint4* L4 = (const uint4*)(Wlo + 1 * 65536);
            f32x4 acc[2] = {};
            #pragma unroll
            for (int ks = 0; ks < 8; ++ks) {
                short8 a_h = lds_frag(sm.g.bHi + aoff + ks * 32);
                short8 a_l = lds_frag(sm.g.bLo + aoff + ks * 32);
                #pragma unroll
                for (int ti = 0; ti < 2; ++ti) {
                    int off = ((w * 2 + ti) * 8 + ks) * 64 + lane;
                    V8 bh, bl; bh.u = H4[off]; bl.u = L4[off];
                    acc[ti] = __builtin_amdgcn_mfma_f32_16x16x32_bf16(a_h, bh.s, acc[ti], 0, 0, 0);
                    acc[ti] = __builtin_amdgcn_mfma_f32_16x16x32_bf16(a_l, bh.s, acc[ti], 0, 0, 0);
                    acc[ti] = __builtin_amdgcn_mfma_f32_16x16x32_bf16(a_h, bl.s, acc[ti], 0, 0, 0);
                }
            }
            __syncthreads();
            #pragma unroll
            for (int ti = 0; ti < 2; ++ti) {
                int n0 = (w * 2 + ti) * 16 + lr;
                float bb = b2[n0];
                #pragma unroll
                for (int r = 0; r < 4; ++r) {
                    float o = acc[ti][r] + bb;
                    ushort hh, ll; split_bf16(o, hh, ll);
                    int ad = (quad * 4 + r) * 264 + n0;
                    sm.g.aHi[ad] = hh; sm.g.aLo[ad] = ll;
                }
            }
        }
        __syncthreads();
        // stage 3: qkv -> bf16 global
        {
            const uint4* Hq = (const uint4*)(Whi + 2 * 65536);
            const uint4* Lq = (const uint4*)(Wlo + 2 * 65536);
            const uint4* Hk = (const uint4*)(Whi + 3 * 65536);
            const uint4* Lk = (const uint4*)(Wlo + 3 * 65536);
            const uint4* Hv = (const uint4*)(Whi + 4 * 65536);
            const uint4* Lv = (const uint4*)(Wlo + 4 * 65536);
            f32x4 aq[2] = {}, ak[2] = {}, av[2] = {};
            #pragma unroll 2
            for (int ks = 0; ks < 8; ++ks) {
                short8 a_h = lds_frag(sm.g.aHi + aoff + ks * 32);
                short8 a_l = lds_frag(sm.g.aLo + aoff + ks * 32);
                #pragma unroll
                for (int ti = 0; ti < 2; ++ti) {
                    int off = ((w * 2 + ti) * 8 + ks) * 64 + lane;
                    V8 qh, ql, kh, kl, vh, vl;
                    qh.u = Hq[off]; ql.u = Lq[off];
                    kh.u = Hk[off]; kl.u = Lk[off];
                    vh.u = Hv[off]; vl.u = Lv[off];
                    aq[ti] = __builtin_amdgcn_mfma_f32_16x16x32_bf16(a_h, qh.s, aq[ti], 0, 0, 0);
                    aq[ti] = __builtin_amdgcn_mfma_f32_16x16x32_bf16(a_l, qh.s, aq[ti], 0, 0, 0);
                    aq[ti] = __builtin_amdgcn_mfma_f32_16x16x32_bf16(a_h, ql.s, aq[ti], 0, 0, 0);
                    ak[ti] = __builtin_amdgcn_mfma_f32_16x16x32_bf16(a_h, kh.s, ak[ti], 0, 0, 0);
                    ak[ti] = __builtin_amdgcn_mfma_f32_16x16x32_bf16(a_l, kh.s, ak[ti], 0, 0, 0);
                    ak[ti] = __builtin_amdgcn_mfma_f32_16x16x32_bf16(a_h, kl.s, ak[ti], 0, 0, 0);
                    av[ti] = __builtin_amdgcn_mfma_f32_16x16x32_bf16(a_h, vh.s, av[ti], 0, 0, 0);
                    av[ti] = __builtin_amdgcn_mfma_f32_16x16x32_bf16(a_l, vh.s, av[ti], 0, 0, 0);
                    av[ti] = __builtin_amdgcn_mfma_f32_16x16x32_bf16(a_h, vl.s, av[ti], 0, 0, 0);
                }
            }
            #pragma unroll
            for (int ti = 0; ti < 2; ++ti) {
                int n0 = (w * 2 + ti) * 16 + lr;
                float bq = Bq[n0], bk = Bk[n0], bv = Bv[n0];
                #pragma unroll
                for (int r = 0; r < 4; ++r) {
                    int go = (r0 + quad * 4 + r) * 256 + n0;
                    Q[go] = bf16bits(aq[ti][r] + bq);
                    K[go] = bf16bits(ak[ti][r] + bk);
                    V[go] = bf16bits(av[ti][r] + bv);
                }
            }
        }
    } else {
        // ================= conn: 32i x 16j tile (identical to R11) ========
        int idx = bx - 256;                 // 0..255
        int h = idx >> 5;
        int rem = idx & 31;
        int it = rem >> 3, jt = rem & 7;
        int i0 = it * 32, j0 = jt * 16;
        int jl = t & 15, il = t >> 4;
        #pragma unroll
        for (int p = 0; p < 6; ++p) {
            int id2 = p * 512 + t;
            if (id2 < 1024) {
                int rr = id2 >> 6, c = (id2 & 63) * 4;
                *(float4*)(sm.c.sA + rr * 260 + c) =
                    *(const float4*)(A + (h * 128 + j0 + rr) * 256 + c);
            } else {
                int id3 = id2 - 1024;
                int rr = id3 >> 6, c = (id3 & 63) * 4;
                float4 bv = *(const float4*)(Bmat + (h * 128 + i0 + rr) * 256 + c);
                float4 fb = *(const float4*)(fc_out_b + c);
                bv.x += fb.x; bv.y += fb.y; bv.z += fb.z; bv.w += fb.w;
                *(float4*)(sm.c.sB + rr * 260 + c) = bv;
            }
        }
        __syncthreads();
        const float* Ar = sm.c.sA + jl * 260;
        const float* Br = sm.c.sB + il * 260;
        float l0 = fc_cat_b[0], l1 = fc_cat_b[1];
        #pragma unroll 4
        for (int d4 = 0; d4 < 64; ++d4) {
            int d = d4 * 4;
            float4 av = *(const float4*)(Ar + d);
            float4 bv = *(const float4*)(Br + d);
            float4 cwA = *(const float4*)(fc_cat_w + d * 2);
            float4 cwB = *(const float4*)(fc_cat_w + d * 2 + 4);
            float h0 = fmaxf(av.x + bv.x, 0.f);
            float h1 = fmaxf(av.y + bv.y, 0.f);
            float h2 = fmaxf(av.z + bv.z, 0.f);
            float h3 = fmaxf(av.w + bv.w, 0.f);
            l0 += h0 * cwA.x + h1 * cwA.z + h2 * cwB.x + h3 * cwB.z;
            l1 += h0 * cwA.y + h1 * cwA.w + h2 * cwB.y + h3 * cwB.w;
        }
        int i = i0 + il, j = j0 + jl;
        float2 uu = *(const float2*)(gumbel_u + ((h * 128 + i) * 128 + j) * 2);
        float g0 = -logf(-logf(uu.x + 1e-10f) + 1e-10f);
        float g1 = -logf(-logf(uu.y + 1e-10f) + 1e-10f);
        bool on = (l1 + g1) > (l0 + g0);
        maskb[(h * 128 + i) * 128 + j] = bf16bits(on ? 0.f : -1e9f);
    }
}

// ---------------------------------------------------------------------------
// Dispatch 3: MFMA attention on bf16 Q/K/V. grid 512 = (b, h, rowhalf);
// 256 thr = 4 waves; wave w -> row tile rt = rh*4 + w.
// ---------------------------------------------------------------------------
__global__ __launch_bounds__(256) void k_attn_mfma(
    const ushort* __restrict__ Q, const ushort* __restrict__ K,
    const ushort* __restrict__ V, const ushort* __restrict__ maskb,
    float* __restrict__ AO) {
    int bx = blockIdx.x;
    int b = bx >> 4, h = (bx >> 1) & 7, rh = bx & 1;
    int t = threadIdx.x;
    int lane = t & 63, w = t >> 6;
    __shared__ __align__(16) ushort vT[32 * 136];
    __shared__ __align__(16) ushort ps[64 * 136];
    #pragma unroll
    for (int it = 0; it < 2; ++it) {
        int idx = it * 256 + t;
        int key = idx >> 2, dq8 = (idx & 3) * 8;
        V8 vv; vv.u = *(const uint4*)(V + (b * 128 + key) * 256 + h * 32 + dq8);
        #pragma unroll
        for (int m = 0; m < 8; ++m)
            vT[(dq8 + m) * 136 + key] = (ushort)vv.s[m];
    }
    __syncthreads();
    int lr = lane & 15, quad = lane >> 4;
    int rt = rh * 4 + w;
    V8 af;
    af.u = *(const uint4*)(Q + (b * 128 + rt * 16 + lr) * 256 + h * 32 + quad * 8);
    f32x4 s[8];
    #pragma unroll
    for (int ct = 0; ct < 8; ++ct) {
        V8 bf_;
        bf_.u = *(const uint4*)(K + (b * 128 + ct * 16 + lr) * 256 + h * 32 + quad * 8);
        f32x4 z = {0.f, 0.f, 0.f, 0.f};
        s[ct] = __builtin_amdgcn_mfma_f32_16x16x32_bf16(af.s, bf_.s, z, 0, 0, 0);
    }
    const float scale = 0.17677669529663687f;  // 32^-0.5
    const ushort* mrow = maskb + h * 16384;
    #pragma unroll
    for (int r = 0; r < 4; ++r) {
        int lrow = w * 16 + quad * 4 + r;
        int grow = rt * 16 + quad * 4 + r;
        float sv[8];
        float mx = -3.0e38f;
        #pragma unroll
        for (int ct = 0; ct < 8; ++ct) {
            float bias = bits_to_f(mrow[grow * 128 + ct * 16 + lr]);
            sv[ct] = s[ct][r] * scale + bias;
            mx = fmaxf(mx, sv[ct]);
        }
        mx = fmaxf(mx, __shfl_xor(mx, 1));
        mx = fmaxf(mx, __shfl_xor(mx, 2));
        mx = fmaxf(mx, __shfl_xor(mx, 4));
        mx = fmaxf(mx, __shfl_xor(mx, 8));
        float sum = 0.f;
        #pragma unroll
        for (int ct = 0; ct < 8; ++ct) {
            sv[ct] = __expf(sv[ct] - mx);
            sum += sv[ct];
        }
        sum += __shfl_xor(sum, 1);
        sum += __shfl_xor(sum, 2);
        sum += __shfl_xor(sum, 4);
        sum += __shfl_xor(sum, 8);
        float iv = 1.f / sum;
        #pragma unroll
        for (int ct = 0; ct < 8; ++ct)
            ps[lrow * 136 + ct * 16 + lr] = bf16bits(sv[ct] * iv);
    }
    f32x4 o0 = {}, o1 = {};
    #pragma unroll
    for (int kk = 0; kk < 4; ++kk) {
        short8 pa = lds_frag(ps + (w * 16 + lr) * 136 + kk * 32 + quad * 8);
        short8 v0 = lds_frag(vT + lr * 136 + kk * 32 + quad * 8);
        short8 v1 = lds_frag(vT + (16 + lr) * 136 + kk * 32 + quad * 8);
        o0 = __builtin_amdgcn_mfma_f32_16x16x32_bf16(pa, v0, o0, 0, 0, 0);
        o1 = __builtin_amdgcn_mfma_f32_16x16x32_bf16(pa, v1, o1, 0, 0, 0);
    }
    #pragma unroll
    for (int r = 0; r < 4; ++r) {
        int grow = rt * 16 + quad * 4 + r;
        float* op = AO + b * 32768 + grow * 256 + h * 32;
        op[lr] = o0[r];
        op[16 + lr] = o1[r];
    }
}

// ---------------------------------------------------------------------------
// Dispatch 4: out-proj GEMM. grid (256 rowtiles, 4 colquads), 256 thr.
// ---------------------------------------------------------------------------
__global__ __launch_bounds__(256) void k_gemm16(
    const float* __restrict__ X, const ushort* __restrict__ Whi,
    const ushort* __restrict__ Wlo, const float* __restrict__ bias,
    float* __restrict__ Y) {
    __shared__ __align__(16) ushort xhi[16 * 264], xlo[16 * 264];
    int t = threadIdx.x;
    int r0 = blockIdx.x * 16;
    #pragma unroll
    for (int ii = 0; ii < 4; ++ii) {
        int f4 = ii * 256 + t;
        int row = f4 >> 6, c = (f4 & 63) * 4;
        float4 xv = *(const float4*)(X + (r0 + row) * 256 + c);
        ushort h[4], l[4];
        split_bf16(xv.x, h[0], l[0]); split_bf16(xv.y, h[1], l[1]);
        split_bf16(xv.z, h[2], l[2]); split_bf16(xv.w, h[3], l[3]);
        uint2 ph = { (uint)h[0] | ((uint)h[1] << 16), (uint)h[2] | ((uint)h[3] << 16) };
        uint2 pl = { (uint)l[0] | ((uint)l[1] << 16), (uint)l[2] | ((uint)l[3] << 16) };
        *(uint2*)(xhi + row * 264 + c) = ph;
        *(uint2*)(xlo + row * 264 + c) = pl;
    }
    __syncthreads();
    int l = t & 63, w = t >> 6;
    int lr = l & 15, quad = l >> 4;
    int tg = blockIdx.y * 4 + w;
    const ushort* ah = xhi + lr * 264 + quad * 8;
    const ushort* al = xlo + lr * 264 + quad * 8;
    const uint4* H4 = (const uint4*)Whi;
    const uint4* L4 = (const uint4*)Wlo;
    f32x4 acc = {};
    #pragma unroll
    for (int ks = 0; ks < 8; ++ks) {
        short8 a_h = lds_frag(ah + ks * 32);
        short8 a_l = lds_frag(al + ks * 32);
        int off = (tg * 8 + ks) * 64 + l;
        V8 bh, bl; bh.u = H4[off]; bl.u = L4[off];
        acc = __builtin_amdgcn_mfma_f32_16x16x32_bf16(a_h, bh.s, acc, 0, 0, 0);
        acc = __builtin_amdgcn_mfma_f32_16x16x32_bf16(a_l, bh.s, acc, 0, 0, 0);
        acc = __builtin_amdgcn_mfma_f32_16x16x32_bf16(a_h, bl.s, acc, 0, 0, 0);
    }
    int n0 = tg * 16 + lr;
    float bs = bias[n0];
    #pragma unroll
    for (int r = 0; r < 4; ++r)
        Y[(r0 + quad * 4 + r) * 256 + n0] = acc[r] + bs;
}

// ---------------------------------------------------------------------------
extern "C" void kernel_launch(void* const* d_in, const int* in_sizes, int n_in,
                              void* d_out, int out_size, void* d_ws, size_t ws_size,
                              hipStream_t stream) {
    const float* x        = (const float*)d_in[0];
    const float* gumbel_u = (const float*)d_in[1];
    const float* memory_w = (const float*)d_in[2];
    const float* fc_out_w = (const float*)d_in[3];
    const float* fc_out_b = (const float*)d_in[4];
    const float* fc_cat_w = (const float*)d_in[5];
    const float* fc_cat_b = (const float*)d_in[6];
    const float* wq       = (const float*)d_in[7];
    const float* bq       = (const float*)d_in[8];
    const float* wk       = (const float*)d_in[9];
    const float* bk       = (const float*)d_in[10];
    const float* wv_      = (const float*)d_in[11];
    const float* bv_      = (const float*)d_in[12];
    const float* out_w    = (const float*)d_in[13];
    const float* out_b    = (const float*)d_in[14];
    const float* mlp_w1   = (const float*)d_in[15];
    const float* mlp_b1   = (const float*)d_in[16];
    const float* mlp_w2   = (const float*)d_in[17];
    const float* mlp_b2   = (const float*)d_in[18];

    // Workspace (floats). 1,048,576 ushorts = 524,288 floats.
    float* ws    = (float*)d_ws;
    float* A     = ws;                        //        0 .. 262144
    float* Bm    = ws + 262144;               //   262144 .. 524288
    ushort* mask = (ushort*)(ws + 524288);    //   524288 .. 589824
    ushort* qb   = (ushort*)(ws + 589824);    //   589824 .. 1114112
    ushort* kb   = (ushort*)(ws + 1114112);   //  1114112 .. 1638400
    ushort* vb   = (ushort*)(ws + 1638400);   //  1638400 .. 2162688
    float* ao    = ws + 2162688;              //  2162688 .. 3211264
    ushort* wf_hi = (ushort*)(ws + 3211264);  //  3211264 .. 3473408
    ushort* wf_lo = wf_hi + 8 * 65536;        //  3473408 .. 3735552
    float* out   = (float*)d_out;

    // DAG (4 levels): {wprep, featproj} -> {fused3, conn} -> attn -> gemm16.
    k_d1<<<dim3(112), dim3(512), 0, stream>>>(
        mlp_w1, mlp_w2, wq, wk, wv_, out_w, fc_out_w, memory_w,
        wf_hi, wf_lo, A, Bm);
    k_d2<<<dim3(512), dim3(512), 0, stream>>>(
        x, wf_hi, wf_lo, mlp_b1, mlp_b2, bq, bk, bv_, qb, kb, vb,
        A, Bm, fc_out_b, fc_cat_w, fc_cat_b, gumbel_u, mask);
    k_attn_mfma<<<dim3(512), dim3(256), 0, stream>>>(qb, kb, vb, mask, ao);
    k_gemm16<<<dim3(256, 4), dim3(256), 0, stream>>>(ao, wf_hi + 5 * 65536,
                                                     wf_lo + 5 * 65536, out_b, out);
}

// Round 13
// 144.686 us; speedup vs baseline: 1.0458x; 1.0458x over previous
//
#include <hip/hip_runtime.h>
#include <hip/hip_bf16.h>
#include <math.h>

// Problem constants: H=8, d_model=256, N=128, d_k=32, B=32, rows=4096

typedef short short8 __attribute__((ext_vector_type(8)));
typedef float f32x4 __attribute__((ext_vector_type(4)));

union V8 { uint4 u; short8 s; };

__device__ __forceinline__ float gelu_f(float x) {
    float inner = 0.7978845608028654f * (x + 0.044715f * x * x * x);
    return 0.5f * x * (1.0f + tanhf(inner));
}
__device__ __forceinline__ void split_bf16(float x, ushort& h, ushort& l) {
    __hip_bfloat16 bh = __float2bfloat16(x);          // RN
    float hf = __bfloat162float(bh);
    __hip_bfloat16 bl = __float2bfloat16(x - hf);
    h = __builtin_bit_cast(ushort, bh);
    l = __builtin_bit_cast(ushort, bl);
}
__device__ __forceinline__ ushort bf16bits(float x) {
    return __builtin_bit_cast(ushort, __float2bfloat16(x));
}
__device__ __forceinline__ float bits_to_f(ushort v) {
    return __builtin_bit_cast(float, ((uint)v) << 16);
}
__device__ __forceinline__ short8 lds_frag(const ushort* p) {
    V8 v; v.u = *(const uint4*)p; return v.s;
}

// Frag layout for all prepped weights: elem (k,n) of mat m lives at
//   m*65536 + ((tg*8+ks)*64 + lane)*8 + j
// with tg=n>>4, lr=n&15, ks=k>>5, quad=(k>>3)&3, j=k&7, lane=quad*16+lr.
// Mats: 0=mlp_w1 1=mlp_w2 2=wq 3=wk 4=wv 5=out_w 6=fc_out_w[0:256] 7=[256:512]
//
// R12 lesson: folding wprep's mats-6/7 conversion into featproj (to cut one
// dispatch) made every featproj block re-convert the whole matrix (64x
// redundant) — regressed 144.6 -> 151.3 µs. Shared prep amortizes; keep it.

// ---------------------------------------------------------------------------
// Dispatch 1: wprep only (64 blocks x 512 thr, two 256-thr jobs per block).
// MUST be its own dispatch: featproj/fused3 read its output (R10's race).
// ---------------------------------------------------------------------------
__global__ __launch_bounds__(512) void k_wprep(
    const float* __restrict__ mlp_w1, const float* __restrict__ mlp_w2,
    const float* __restrict__ wq, const float* __restrict__ wk,
    const float* __restrict__ wv, const float* __restrict__ out_w,
    const float* __restrict__ fc_out_w,
    ushort* __restrict__ hi, ushort* __restrict__ lo) {
    __shared__ __align__(16) float xs2[2][32 * 132];
    int bx = blockIdx.x, t = threadIdx.x;
    int half = t >> 8, tl = t & 255;
    int job = bx * 2 + half;                      // 0..127
    int m = job >> 4, ks = (job >> 1) & 7, nh = job & 1;
    const float* W = m == 0 ? mlp_w1 : m == 1 ? mlp_w2 : m == 2 ? wq :
                     m == 3 ? wk : m == 4 ? wv : m == 5 ? out_w :
                     m == 6 ? fc_out_w : fc_out_w + 65536;
    ushort* Hm = hi + m * 65536;
    ushort* Lm = lo + m * 65536;
    float* xs = xs2[half];
    #pragma unroll
    for (int p = 0; p < 4; ++p) {
        int idx = p * 256 + tl;
        int row = idx >> 5, c4 = (idx & 31) * 4;
        *(float4*)(xs + row * 132 + c4) =
            *(const float4*)(W + (ks * 32 + row) * 256 + nh * 128 + c4);
    }
    __syncthreads();
    int lane = tl & 63, lr = lane & 15, quad = lane >> 4;
    #pragma unroll
    for (int it = 0; it < 2; ++it) {
        int tgl = (tl >> 6) + 4 * it;
        int tg = nh * 8 + tgl;
        int nl = tgl * 16 + lr;
        ushort hb[8], lb[8];
        #pragma unroll
        for (int j = 0; j < 8; ++j)
            split_bf16(xs[(quad * 8 + j) * 132 + nl], hb[j], lb[j]);
        uint4 ph = { (uint)hb[0] | ((uint)hb[1] << 16), (uint)hb[2] | ((uint)hb[3] << 16),
                     (uint)hb[4] | ((uint)hb[5] << 16), (uint)hb[6] | ((uint)hb[7] << 16) };
        uint4 pl = { (uint)lb[0] | ((uint)lb[1] << 16), (uint)lb[2] | ((uint)lb[3] << 16),
                     (uint)lb[4] | ((uint)lb[5] << 16), (uint)lb[6] | ((uint)lb[7] << 16) };
        int idx = ((tg * 8 + ks) * 64 + lane) * 8;
        *(uint4*)(Hm + idx) = ph;
        *(uint4*)(Lm + idx) = pl;
    }
}

// ---------------------------------------------------------------------------
// Dispatch 2: blocks 0..63 = featproj (stage once, 8 waves cover all jobs);
//             blocks 64..319 = fused3 (mlp1->mlp2->qkv, bf16 out).
// Both only READ wf_hi/wf_lo (D1 output); writes are disjoint. 512 threads.
// ---------------------------------------------------------------------------
__global__ __launch_bounds__(512) void k_p2(
    const float* __restrict__ memory_w, const float* __restrict__ X,
    const ushort* __restrict__ Whi, const ushort* __restrict__ Wlo,
    const float* __restrict__ b1, const float* __restrict__ b2,
    const float* __restrict__ Bq, const float* __restrict__ Bk,
    const float* __restrict__ Bv,
    float* __restrict__ A, float* __restrict__ Bm,
    ushort* __restrict__ Q, ushort* __restrict__ K, ushort* __restrict__ V) {
    __shared__ __align__(16) union {
        struct { ushort xhi[16 * 264], xlo[16 * 264]; } f;   // featproj 16.9 KB
        struct {
            ushort aHi[16 * 264], aLo[16 * 264];
            ushort bHi[16 * 264], bLo[16 * 264];
        } g;                                                  // fused3 33.8 KB
    } sm;
    int bx = blockIdx.x, t = threadIdx.x;
    if (bx < 64) {
        // ---- featproj: rt = bx; one staged tile serves all 8 (msel,cq)
        int rt = bx;
        #pragma unroll
        for (int ii = 0; ii < 2; ++ii) {
            int f4 = ii * 512 + t;
            int rr = f4 >> 6, c = (f4 & 63) * 4;
            int r = rt * 16 + rr;
            int h = r >> 7, n = r & 127;
            float4 xv = *(const float4*)(memory_w + n * 2048 + h * 256 + c);
            ushort hh[4], ll[4];
            split_bf16(xv.x, hh[0], ll[0]); split_bf16(xv.y, hh[1], ll[1]);
            split_bf16(xv.z, hh[2], ll[2]); split_bf16(xv.w, hh[3], ll[3]);
            uint2 ph = { (uint)hh[0] | ((uint)hh[1] << 16), (uint)hh[2] | ((uint)hh[3] << 16) };
            uint2 pl = { (uint)ll[0] | ((uint)ll[1] << 16), (uint)ll[2] | ((uint)ll[3] << 16) };
            *(uint2*)(sm.f.xhi + rr * 264 + c) = ph;
            *(uint2*)(sm.f.xlo + rr * 264 + c) = pl;
        }
        __syncthreads();
        int lane = t & 63, w = t >> 6;
        int lr = lane & 15, quad = lane >> 4;
        int msel = w & 1, cq = w >> 1;
        const uint4* H4 = (const uint4*)(Whi + (6 + msel) * 65536);
        const uint4* L4 = (const uint4*)(Wlo + (6 + msel) * 65536);
        const ushort* ah = sm.f.xhi + lr * 264 + quad * 8;
        const ushort* al = sm.f.xlo + lr * 264 + quad * 8;
        float* O = msel ? Bm : A;
        #pragma unroll
        for (int i = 0; i < 4; ++i) {
            int tg = cq * 4 + i;
            f32x4 acc = {};
            #pragma unroll
            for (int ks = 0; ks < 8; ++ks) {
                short8 a_h = lds_frag(ah + ks * 32);
                short8 a_l = lds_frag(al + ks * 32);
                int off = (tg * 8 + ks) * 64 + lane;
                V8 bh, bl; bh.u = H4[off]; bl.u = L4[off];
                acc = __builtin_amdgcn_mfma_f32_16x16x32_bf16(a_h, bh.s, acc, 0, 0, 0);
                acc = __builtin_amdgcn_mfma_f32_16x16x32_bf16(a_l, bh.s, acc, 0, 0, 0);
                acc = __builtin_amdgcn_mfma_f32_16x16x32_bf16(a_h, bl.s, acc, 0, 0, 0);
            }
            int n0 = tg * 16 + lr;
            #pragma unroll
            for (int r = 0; r < 4; ++r)
                O[(rt * 16 + quad * 4 + r) * 256 + n0] = acc[r];
        }
        return;
    }
    // ================= fused3 (identical math to R9) =================
    int r0 = (bx - 64) * 16;
    #pragma unroll
    for (int ii = 0; ii < 2; ++ii) {
        int f4 = ii * 512 + t;
        int row = f4 >> 6, c = (f4 & 63) * 4;
        float4 xv = *(const float4*)(X + (r0 + row) * 256 + c);
        ushort h[4], l[4];
        split_bf16(xv.x, h[0], l[0]); split_bf16(xv.y, h[1], l[1]);
        split_bf16(xv.z, h[2], l[2]); split_bf16(xv.w, h[3], l[3]);
        uint2 ph = { (uint)h[0] | ((uint)h[1] << 16), (uint)h[2] | ((uint)h[3] << 16) };
        uint2 pl = { (uint)l[0] | ((uint)l[1] << 16), (uint)l[2] | ((uint)l[3] << 16) };
        *(uint2*)(sm.g.aHi + row * 264 + c) = ph;
        *(uint2*)(sm.g.aLo + row * 264 + c) = pl;
    }
    __syncthreads();
    int lane = t & 63, w = t >> 6;
    int lr = lane & 15, quad = lane >> 4;
    int aoff = lr * 264 + quad * 8;
    // stage 1: mlp1 + gelu
    {
        const uint4* H4 = (const uint4*)(Whi + 0 * 65536);
        const uint4* L4 = (const uint4*)(Wlo + 0 * 65536);
        f32x4 acc[2] = {};
        #pragma unroll
        for (int ks = 0; ks < 8; ++ks) {
            short8 a_h = lds_frag(sm.g.aHi + aoff + ks * 32);
            short8 a_l = lds_frag(sm.g.aLo + aoff + ks * 32);
            #pragma unroll
            for (int ti = 0; ti < 2; ++ti) {
                int off = ((w * 2 + ti) * 8 + ks) * 64 + lane;
                V8 bh, bl; bh.u = H4[off]; bl.u = L4[off];
                acc[ti] = __builtin_amdgcn_mfma_f32_16x16x32_bf16(a_h, bh.s, acc[ti], 0, 0, 0);
                acc[ti] = __builtin_amdgcn_mfma_f32_16x16x32_bf16(a_l, bh.s, acc[ti], 0, 0, 0);
                acc[ti] = __builtin_amdgcn_mfma_f32_16x16x32_bf16(a_h, bl.s, acc[ti], 0, 0, 0);
            }
        }
        #pragma unroll
        for (int ti = 0; ti < 2; ++ti) {
            int n0 = (w * 2 + ti) * 16 + lr;
            float bb = b1[n0];
            #pragma unroll
            for (int r = 0; r < 4; ++r) {
                float o = gelu_f(acc[ti][r] + bb);
                ushort hh, ll; split_bf16(o, hh, ll);
                int ad = (quad * 4 + r) * 264 + n0;
                sm.g.bHi[ad] = hh; sm.g.bLo[ad] = ll;
            }
        }
    }
    __syncthreads();
    // stage 2: mlp2
    {
        const uint4* H4 = (const uint4*)(Whi + 1 * 65536);
        const uint4* L4 = (const uint4*)(Wlo + 1 * 65536);
        f32x4 acc[2] = {};
        #pragma unroll
        for (int ks = 0; ks < 8; ++ks) {
            short8 a_h = lds_frag(sm.g.bHi + aoff + ks * 32);
            short8 a_l = lds_frag(sm.g.bLo + aoff + ks * 32);
            #pragma unroll
            for (int ti = 0; ti < 2; ++ti) {
                int off = ((w * 2 + ti) * 8 + ks) * 64 + lane;
                V8 bh, bl; bh.u = H4[off]; bl.u = L4[off];
                acc[ti] = __builtin_amdgcn_mfma_f32_16x16x32_bf16(a_h, bh.s, acc[ti], 0, 0, 0);
                acc[ti] = __builtin_amdgcn_mfma_f32_16x16x32_bf16(a_l, bh.s, acc[ti], 0, 0, 0);
                acc[ti] = __builtin_amdgcn_mfma_f32_16x16x32_bf16(a_h, bl.s, acc[ti], 0, 0, 0);
            }
        }
        __syncthreads();
        #pragma unroll
        for (int ti = 0; ti < 2; ++ti) {
            int n0 = (w * 2 + ti) * 16 + lr;
            float bb = b2[n0];
            #pragma unroll
            for (int r = 0; r < 4; ++r) {
                float o = acc[ti][r] + bb;
                ushort hh, ll; split_bf16(o, hh, ll);
                int ad = (quad * 4 + r) * 264 + n0;
                sm.g.aHi[ad] = hh; sm.g.aLo[ad] = ll;
            }
        }
    }
    __syncthreads();
    // stage 3: qkv -> bf16 global
    {
        const uint4* Hq = (const uint4*)(Whi + 2 * 65536);
        const uint4* Lq = (const uint4*)(Wlo + 2 * 65536);
        const uint4* Hk = (const uint4*)(Whi + 3 * 65536);
        const uint4* Lk = (const uint4*)(Wlo + 3 * 65536);
        const uint4* Hv = (const uint4*)(Whi + 4 * 65536);
        const uint4* Lv = (const uint4*)(Wlo + 4 * 65536);
        f32x4 aq[2] = {}, ak[2] = {}, av[2] = {};
        #pragma unroll 2
        for (int ks = 0; ks < 8; ++ks) {
            short8 a_h = lds_frag(sm.g.aHi + aoff + ks * 32);
            short8 a_l = lds_frag(sm.g.aLo + aoff + ks * 32);
            #pragma unroll
            for (int ti = 0; ti < 2; ++ti) {
                int off = ((w * 2 + ti) * 8 + ks) * 64 + lane;
                V8 qh, ql, kh, kl, vh, vl;
                qh.u = Hq[off]; ql.u = Lq[off];
                kh.u = Hk[off]; kl.u = Lk[off];
                vh.u = Hv[off]; vl.u = Lv[off];
                aq[ti] = __builtin_amdgcn_mfma_f32_16x16x32_bf16(a_h, qh.s, aq[ti], 0, 0, 0);
                aq[ti] = __builtin_amdgcn_mfma_f32_16x16x32_bf16(a_l, qh.s, aq[ti], 0, 0, 0);
                aq[ti] = __builtin_amdgcn_mfma_f32_16x16x32_bf16(a_h, ql.s, aq[ti], 0, 0, 0);
                ak[ti] = __builtin_amdgcn_mfma_f32_16x16x32_bf16(a_h, kh.s, ak[ti], 0, 0, 0);
                ak[ti] = __builtin_amdgcn_mfma_f32_16x16x32_bf16(a_l, kh.s, ak[ti], 0, 0, 0);
                ak[ti] = __builtin_amdgcn_mfma_f32_16x16x32_bf16(a_h, kl.s, ak[ti], 0, 0, 0);
                av[ti] = __builtin_amdgcn_mfma_f32_16x16x32_bf16(a_h, vh.s, av[ti], 0, 0, 0);
                av[ti] = __builtin_amdgcn_mfma_f32_16x16x32_bf16(a_l, vh.s, av[ti], 0, 0, 0);
                av[ti] = __builtin_amdgcn_mfma_f32_16x16x32_bf16(a_h, vl.s, av[ti], 0, 0, 0);
            }
        }
        #pragma unroll
        for (int ti = 0; ti < 2; ++ti) {
            int n0 = (w * 2 + ti) * 16 + lr;
            float bq = Bq[n0], bk = Bk[n0], bv = Bv[n0];
            #pragma unroll
            for (int r = 0; r < 4; ++r) {
                int go = (r0 + quad * 4 + r) * 256 + n0;
                Q[go] = bf16bits(aq[ti][r] + bq);
                K[go] = bf16bits(ak[ti][r] + bk);
                V[go] = bf16bits(av[ti][r] + bv);
            }
        }
    }
}

// ---------------------------------------------------------------------------
// Dispatch 3: conn (32i x 16j tiles). 256 blocks x 512 thr.
// ---------------------------------------------------------------------------
__global__ __launch_bounds__(512) void k_conn(
    const float* __restrict__ A, const float* __restrict__ Bmat,
    const float* __restrict__ fc_out_b, const float* __restrict__ fc_cat_w,
    const float* __restrict__ fc_cat_b, const float* __restrict__ gumbel_u,
    ushort* __restrict__ maskb) {
    __shared__ __align__(16) float sA[16 * 260], sB[32 * 260];
    int bx = blockIdx.x, t = threadIdx.x;
    int h = bx >> 5;
    int rem = bx & 31;
    int it = rem >> 3, jt = rem & 7;    // it 0..3, jt 0..7
    int i0 = it * 32, j0 = jt * 16;
    int jl = t & 15, il = t >> 4;       // jl 0..15, il 0..31
    #pragma unroll
    for (int p = 0; p < 6; ++p) {
        int id2 = p * 512 + t;          // 0..3071
        if (id2 < 1024) {
            int rr = id2 >> 6, c = (id2 & 63) * 4;
            *(float4*)(sA + rr * 260 + c) =
                *(const float4*)(A + (h * 128 + j0 + rr) * 256 + c);
        } else {
            int id3 = id2 - 1024;
            int rr = id3 >> 6, c = (id3 & 63) * 4;
            float4 bv = *(const float4*)(Bmat + (h * 128 + i0 + rr) * 256 + c);
            float4 fb = *(const float4*)(fc_out_b + c);
            bv.x += fb.x; bv.y += fb.y; bv.z += fb.z; bv.w += fb.w;
            *(float4*)(sB + rr * 260 + c) = bv;
        }
    }
    __syncthreads();
    const float* Ar = sA + jl * 260;
    const float* Br = sB + il * 260;
    float l0 = fc_cat_b[0], l1 = fc_cat_b[1];
    #pragma unroll 4
    for (int d4 = 0; d4 < 64; ++d4) {
        int d = d4 * 4;
        float4 av = *(const float4*)(Ar + d);
        float4 bv = *(const float4*)(Br + d);
        float4 cwA = *(const float4*)(fc_cat_w + d * 2);
        float4 cwB = *(const float4*)(fc_cat_w + d * 2 + 4);
        float h0 = fmaxf(av.x + bv.x, 0.f);
        float h1 = fmaxf(av.y + bv.y, 0.f);
        float h2 = fmaxf(av.z + bv.z, 0.f);
        float h3 = fmaxf(av.w + bv.w, 0.f);
        l0 += h0 * cwA.x + h1 * cwA.z + h2 * cwB.x + h3 * cwB.z;
        l1 += h0 * cwA.y + h1 * cwA.w + h2 * cwB.y + h3 * cwB.w;
    }
    int i = i0 + il, j = j0 + jl;
    float2 uu = *(const float2*)(gumbel_u + ((h * 128 + i) * 128 + j) * 2);
    float g0 = -logf(-logf(uu.x + 1e-10f) + 1e-10f);
    float g1 = -logf(-logf(uu.y + 1e-10f) + 1e-10f);
    bool on = (l1 + g1) > (l0 + g0);
    maskb[(h * 128 + i) * 128 + j] = bf16bits(on ? 0.f : -1e9f);
}

// ---------------------------------------------------------------------------
// Dispatch 4: MFMA attention on bf16 Q/K/V. grid 512 = (b, h, rowhalf);
// 256 thr = 4 waves; wave w -> row tile rt = rh*4 + w.
// ---------------------------------------------------------------------------
__global__ __launch_bounds__(256) void k_attn_mfma(
    const ushort* __restrict__ Q, const ushort* __restrict__ K,
    const ushort* __restrict__ V, const ushort* __restrict__ maskb,
    float* __restrict__ AO) {
    int bx = blockIdx.x;
    int b = bx >> 4, h = (bx >> 1) & 7, rh = bx & 1;
    int t = threadIdx.x;
    int lane = t & 63, w = t >> 6;
    __shared__ __align__(16) ushort vT[32 * 136];
    __shared__ __align__(16) ushort ps[64 * 136];
    #pragma unroll
    for (int it = 0; it < 2; ++it) {
        int idx = it * 256 + t;
        int key = idx >> 2, dq8 = (idx & 3) * 8;
        V8 vv; vv.u = *(const uint4*)(V + (b * 128 + key) * 256 + h * 32 + dq8);
        #pragma unroll
        for (int m = 0; m < 8; ++m)
            vT[(dq8 + m) * 136 + key] = (ushort)vv.s[m];
    }
    __syncthreads();
    int lr = lane & 15, quad = lane >> 4;
    int rt = rh * 4 + w;
    V8 af;
    af.u = *(const uint4*)(Q + (b * 128 + rt * 16 + lr) * 256 + h * 32 + quad * 8);
    f32x4 s[8];
    #pragma unroll
    for (int ct = 0; ct < 8; ++ct) {
        V8 bf_;
        bf_.u = *(const uint4*)(K + (b * 128 + ct * 16 + lr) * 256 + h * 32 + quad * 8);
        f32x4 z = {0.f, 0.f, 0.f, 0.f};
        s[ct] = __builtin_amdgcn_mfma_f32_16x16x32_bf16(af.s, bf_.s, z, 0, 0, 0);
    }
    const float scale = 0.17677669529663687f;  // 32^-0.5
    const ushort* mrow = maskb + h * 16384;
    #pragma unroll
    for (int r = 0; r < 4; ++r) {
        int lrow = w * 16 + quad * 4 + r;
        int grow = rt * 16 + quad * 4 + r;
        float sv[8];
        float mx = -3.0e38f;
        #pragma unroll
        for (int ct = 0; ct < 8; ++ct) {
            float bias = bits_to_f(mrow[grow * 128 + ct * 16 + lr]);
            sv[ct] = s[ct][r] * scale + bias;
            mx = fmaxf(mx, sv[ct]);
        }
        mx = fmaxf(mx, __shfl_xor(mx, 1));
        mx = fmaxf(mx, __shfl_xor(mx, 2));
        mx = fmaxf(mx, __shfl_xor(mx, 4));
        mx = fmaxf(mx, __shfl_xor(mx, 8));
        float sum = 0.f;
        #pragma unroll
        for (int ct = 0; ct < 8; ++ct) {
            sv[ct] = __expf(sv[ct] - mx);
            sum += sv[ct];
        }
        sum += __shfl_xor(sum, 1);
        sum += __shfl_xor(sum, 2);
        sum += __shfl_xor(sum, 4);
        sum += __shfl_xor(sum, 8);
        float iv = 1.f / sum;
        #pragma unroll
        for (int ct = 0; ct < 8; ++ct)
            ps[lrow * 136 + ct * 16 + lr] = bf16bits(sv[ct] * iv);
    }
    f32x4 o0 = {}, o1 = {};
    #pragma unroll
    for (int kk = 0; kk < 4; ++kk) {
        short8 pa = lds_frag(ps + (w * 16 + lr) * 136 + kk * 32 + quad * 8);
        short8 v0 = lds_frag(vT + lr * 136 + kk * 32 + quad * 8);
        short8 v1 = lds_frag(vT + (16 + lr) * 136 + kk * 32 + quad * 8);
        o0 = __builtin_amdgcn_mfma_f32_16x16x32_bf16(pa, v0, o0, 0, 0, 0);
        o1 = __builtin_amdgcn_mfma_f32_16x16x32_bf16(pa, v1, o1, 0, 0, 0);
    }
    #pragma unroll
    for (int r = 0; r < 4; ++r) {
        int grow = rt * 16 + quad * 4 + r;
        float* op = AO + b * 32768 + grow * 256 + h * 32;
        op[lr] = o0[r];
        op[16 + lr] = o1[r];
    }
}

// ---------------------------------------------------------------------------
// Dispatch 5: out-proj GEMM. grid (256 rowtiles, 4 colquads), 256 thr.
// ---------------------------------------------------------------------------
__global__ __launch_bounds__(256) void k_gemm16(
    const float* __restrict__ X, const ushort* __restrict__ Whi,
    const ushort* __restrict__ Wlo, const float* __restrict__ bias,
    float* __restrict__ Y) {
    __shared__ __align__(16) ushort xhi[16 * 264], xlo[16 * 264];
    int t = threadIdx.x;
    int r0 = blockIdx.x * 16;
    #pragma unroll
    for (int ii = 0; ii < 4; ++ii) {
        int f4 = ii * 256 + t;
        int row = f4 >> 6, c = (f4 & 63) * 4;
        float4 xv = *(const float4*)(X + (r0 + row) * 256 + c);
        ushort h[4], l[4];
        split_bf16(xv.x, h[0], l[0]); split_bf16(xv.y, h[1], l[1]);
        split_bf16(xv.z, h[2], l[2]); split_bf16(xv.w, h[3], l[3]);
        uint2 ph = { (uint)h[0] | ((uint)h[1] << 16), (uint)h[2] | ((uint)h[3] << 16) };
        uint2 pl = { (uint)l[0] | ((uint)l[1] << 16), (uint)l[2] | ((uint)l[3] << 16) };
        *(uint2*)(xhi + row * 264 + c) = ph;
        *(uint2*)(xlo + row * 264 + c) = pl;
    }
    __syncthreads();
    int l = t & 63, w = t >> 6;
    int lr = l & 15, quad = l >> 4;
    int tg = blockIdx.y * 4 + w;
    const ushort* ah = xhi + lr * 264 + quad * 8;
    const ushort* al = xlo + lr * 264 + quad * 8;
    const uint4* H4 = (const uint4*)Whi;
    const uint4* L4 = (const uint4*)Wlo;
    f32x4 acc = {};
    #pragma unroll
    for (int ks = 0; ks < 8; ++ks) {
        short8 a_h = lds_frag(ah + ks * 32);
        short8 a_l = lds_frag(al + ks * 32);
        int off = (tg * 8 + ks) * 64 + l;
        V8 bh, bl; bh.u = H4[off]; bl.u = L4[off];
        acc = __builtin_amdgcn_mfma_f32_16x16x32_bf16(a_h, bh.s, acc, 0, 0, 0);
        acc = __builtin_amdgcn_mfma_f32_16x16x32_bf16(a_l, bh.s, acc, 0, 0, 0);
        acc = __builtin_amdgcn_mfma_f32_16x16x32_bf16(a_h, bl.s, acc, 0, 0, 0);
    }
    int n0 = tg * 16 + lr;
    float bs = bias[n0];
    #pragma unroll
    for (int r = 0; r < 4; ++r)
        Y[(r0 + quad * 4 + r) * 256 + n0] = acc[r] + bs;
}

// ---------------------------------------------------------------------------
extern "C" void kernel_launch(void* const* d_in, const int* in_sizes, int n_in,
                              void* d_out, int out_size, void* d_ws, size_t ws_size,
                              hipStream_t stream) {
    const float* x        = (const float*)d_in[0];
    const float* gumbel_u = (const float*)d_in[1];
    const float* memory_w = (const float*)d_in[2];
    const float* fc_out_w = (const float*)d_in[3];
    const float* fc_out_b = (const float*)d_in[4];
    const float* fc_cat_w = (const float*)d_in[5];
    const float* fc_cat_b = (const float*)d_in[6];
    const float* wq       = (const float*)d_in[7];
    const float* bq       = (const float*)d_in[8];
    const float* wk       = (const float*)d_in[9];
    const float* bk       = (const float*)d_in[10];
    const float* wv_      = (const float*)d_in[11];
    const float* bv_      = (const float*)d_in[12];
    const float* out_w    = (const float*)d_in[13];
    const float* out_b    = (const float*)d_in[14];
    const float* mlp_w1   = (const float*)d_in[15];
    const float* mlp_b1   = (const float*)d_in[16];
    const float* mlp_w2   = (const float*)d_in[17];
    const float* mlp_b2   = (const float*)d_in[18];

    // Workspace (floats). 1,048,576 ushorts = 524,288 floats.
    float* ws    = (float*)d_ws;
    float* A     = ws;                        //        0 .. 262144
    float* Bm    = ws + 262144;               //   262144 .. 524288
    ushort* mask = (ushort*)(ws + 524288);    //   524288 .. 589824
    ushort* qb   = (ushort*)(ws + 589824);    //   589824 .. 1114112
    ushort* kb   = (ushort*)(ws + 1114112);   //  1114112 .. 1638400
    ushort* vb   = (ushort*)(ws + 1638400);   //  1638400 .. 2162688
    float* ao    = ws + 2162688;              //  2162688 .. 3211264
    ushort* wf_hi = (ushort*)(ws + 3211264);  //  3211264 .. 3473408
    ushort* wf_lo = wf_hi + 8 * 65536;        //  3473408 .. 3735552
    float* out   = (float*)d_out;

    // DAG: wprep -> {featproj, fused3} -> conn -> attn -> gemm16 (5 levels).
    k_wprep<<<dim3(64), dim3(512), 0, stream>>>(
        mlp_w1, mlp_w2, wq, wk, wv_, out_w, fc_out_w, wf_hi, wf_lo);
    k_p2<<<dim3(320), dim3(512), 0, stream>>>(
        memory_w, x, wf_hi, wf_lo, mlp_b1, mlp_b2, bq, bk, bv_,
        A, Bm, qb, kb, vb);
    k_conn<<<dim3(256), dim3(512), 0, stream>>>(
        A, Bm, fc_out_b, fc_cat_w, fc_cat_b, gumbel_u, mask);
    k_attn_mfma<<<dim3(512), dim3(256), 0, stream>>>(qb, kb, vb, mask, ao);
    k_gemm16<<<dim3(256, 4), dim3(256), 0, stream>>>(ao, wf_hi + 5 * 65536,
                                                     wf_lo + 5 * 65536, out_b, out);
}